// Round 8
// baseline (218.184 us; speedup 1.0000x reference)
//
#include <hip/hip_runtime.h>

constexpr int FD = 128;
constexpr int NBMAX = 512;   // max coarse buckets (rows/128); n<=65536
constexpr int CH1 = 2048;    // edges per binning block
constexpr int CAPB = 3072;   // per-bucket edge capacity (mean 2048, +22 sigma)

typedef __attribute__((ext_vector_type(8))) short short8;   // 8 bf16 (4 VGPRs)
typedef __attribute__((ext_vector_type(4))) float floatx4;  // MFMA acc

// ---- monotone float<->uint encoding for atomic max over floats ----
__device__ __forceinline__ unsigned fenc(float f) {
    unsigned u = __float_as_uint(f);
    return (u & 0x80000000u) ? ~u : (u | 0x80000000u);
}
__device__ __forceinline__ float fdec(unsigned e) {
    return (e & 0x80000000u) ? __uint_as_float(e & 0x7fffffffu)
                             : __uint_as_float(~e);
}

// RNE pack of two fp32 -> bf16 pair (x in low 16, y in high 16)
__device__ __forceinline__ unsigned bpack(float x, float y) {
    unsigned ux = __float_as_uint(x); ux += 0x7FFFu + ((ux >> 16) & 1u);
    unsigned uy = __float_as_uint(y); uy += 0x7FFFu + ((uy >> 16) & 1u);
    return (ux >> 16) | (uy & 0xFFFF0000u);
}

// ---- W -> bf16 rows (Wb) + zero bucket histogram + init max slots ----
__global__ __launch_bounds__(128) void initwt_kernel(const float* __restrict__ W,
                                                     unsigned* __restrict__ Wb,
                                                     int* __restrict__ bhist,
                                                     unsigned* __restrict__ maxslot) {
    int j = blockIdx.x, k = threadIdx.x;
    float w = W[(size_t)j * FD + k];
    float pw = __shfl_xor(w, 1, 64);             // partner k^1 (same wave)
    if ((k & 1) == 0) Wb[(size_t)j * 64 + (k >> 1)] = bpack(w, pw);
    if (j == 0) {
        for (int i = k; i < NBMAX; i += 128) bhist[i] = 0;
        if (k < 2) maxslot[k] = 0x007FFFFFu;     // fenc(-inf)
    }
}

// ---- MFMA GEMM: Whb(bf16) = h @ W^T  (no LDS; frags are contiguous 16B runs) ----
// block = 256 thr = 4 waves; wave = 16 rows x 128 cols (8 col-tiles x 4 K-steps)
__global__ __launch_bounds__(256) void gemm_kernel(const float* __restrict__ h,
                                                   const unsigned* __restrict__ Wb,
                                                   unsigned* __restrict__ Whb, int n) {
    int w = threadIdx.x >> 6, lane = threadIdx.x & 63;
    int quad = lane >> 4, c = lane & 15;
    int rbase = blockIdx.x * 64 + w * 16;

    // A frags: lane holds h[rbase + c][k], k = kk*32 + quad*8 + (0..7), bf16-cast
    int arow = min(rbase + c, n - 1);
    const float4* hrow = (const float4*)(h + (size_t)arow * FD);
    union { uint4 u; short8 s; } af[4];
#pragma unroll
    for (int kk = 0; kk < 4; ++kk) {
        int k0 = kk * 32 + quad * 8;
        float4 f0 = hrow[k0 >> 2];
        float4 f1 = hrow[(k0 >> 2) + 1];
        af[kk].u.x = bpack(f0.x, f0.y);
        af[kk].u.y = bpack(f0.z, f0.w);
        af[kk].u.z = bpack(f1.x, f1.y);
        af[kk].u.w = bpack(f1.z, f1.w);
    }

#pragma unroll
    for (int t = 0; t < 8; ++t) {
        // B frag: lane holds W[t*16 + c][k], k = kk*32 + quad*8 + (0..7)  (L1-resident)
        const uint4* brow = (const uint4*)(Wb + (size_t)(t * 16 + c) * 64 + quad * 4);
        floatx4 acc = {0.f, 0.f, 0.f, 0.f};
#pragma unroll
        for (int kk = 0; kk < 4; ++kk) {
            union { uint4 u; short8 s; } bf;
            bf.u = brow[kk * 4];   // +kk*32 bf16 = +kk*16 uint = +kk*4 uint4
            acc = __builtin_amdgcn_mfma_f32_16x16x32_bf16(af[kk].s, bf.s, acc, 0, 0, 0);
        }
        // D layout: col = lane&15 (-> j = t*16+c), row = quad*4 + i
#pragma unroll
        for (int i = 0; i < 4; ++i) {
            float v = acc[i];
            float pv = __shfl_xor(v, 1, 64);     // partner col j^1
            int r = rbase + quad * 4 + i;
            if ((c & 1) == 0 && r < n)
                Whb[(size_t)r * 64 + t * 8 + (c >> 1)] = bpack(v, pv);
        }
    }
}

// ---- s1/s2 from bf16 Whb (one wave/row, grid-stride) + global max (2 atomics/blk) ----
__global__ __launch_bounds__(256) void s12_kernel(const unsigned* __restrict__ Whb,
                                                  const float* __restrict__ a,
                                                  float* __restrict__ s1,
                                                  float* __restrict__ s2,
                                                  unsigned* __restrict__ maxslot, int n) {
    __shared__ float m1s[4], m2s[4];
    int t = threadIdx.x, w = t >> 6, lane = t & 63;
    float a1x = a[2 * lane], a1y = a[2 * lane + 1];
    float a2x = a[FD + 2 * lane], a2y = a[FD + 2 * lane + 1];
    float m1 = -3.0e38f, m2 = -3.0e38f;
    for (int r = blockIdx.x * 4 + w; r < n; r += gridDim.x * 4) {
        unsigned u = Whb[(size_t)r * 64 + lane];
        float f0 = __uint_as_float(u << 16);
        float f1 = __uint_as_float(u & 0xFFFF0000u);
        float p1 = fmaf(f0, a1x, f1 * a1y);
        float p2 = fmaf(f0, a2x, f1 * a2y);
#pragma unroll
        for (int d = 1; d < 64; d <<= 1) {
            p1 += __shfl_xor(p1, d, 64);
            p2 += __shfl_xor(p2, d, 64);
        }
        if (lane == 0) {
            s1[r] = p1; s2[r] = p2;
            m1 = fmaxf(m1, p1); m2 = fmaxf(m2, p2);
        }
    }
#pragma unroll
    for (int d = 1; d < 64; d <<= 1) {
        m1 = fmaxf(m1, __shfl_xor(m1, d, 64));
        m2 = fmaxf(m2, __shfl_xor(m2, d, 64));
    }
    if (lane == 0) { m1s[w] = m1; m2s[w] = m2; }
    __syncthreads();
    if (t == 0) {
        m1 = fmaxf(fmaxf(m1s[0], m1s[1]), fmaxf(m1s[2], m1s[3]));
        m2 = fmaxf(fmaxf(m2s[0], m2s[1]), fmaxf(m2s[2], m2s[3]));
        atomicMax(&maxslot[0], fenc(m1));
        atomicMax(&maxslot[1], fenc(m2));
    }
}

// ---- pass A: coarse bucket histogram (bucket = row >> 7), LDS-staged ----
__global__ __launch_bounds__(256) void bhist_kernel(const int* __restrict__ ei,
                                                    int* __restrict__ bhist,
                                                    int e_cnt, int nb) {
    __shared__ int h[NBMAX];
    int t = threadIdx.x;
    for (int i = t; i < NBMAX; i += 256) h[i] = 0;
    __syncthreads();
    int base = blockIdx.x * CH1;
    int m = min(CH1, e_cnt - base);
    for (int idx = t; idx < m; idx += 256) {
        int r = ei[base + idx];
        atomicAdd(&h[r >> 7], 1);
    }
    __syncthreads();
    for (int i = t; i < nb; i += 256)
        if (h[i]) atomicAdd(&bhist[i], h[i]);
}

// ---- scan bucket counts -> bstart / bcursor ----
__global__ __launch_bounds__(512) void bscan_kernel(const int* __restrict__ bhist,
                                                    int* __restrict__ bstart,
                                                    int* __restrict__ bcursor,
                                                    int nb, int e_cnt) {
    __shared__ int sc[512];
    int t = threadIdx.x;
    int v = (t < nb) ? bhist[t] : 0;
    sc[t] = v;
    __syncthreads();
    for (int off = 1; off < 512; off <<= 1) {
        int u = (t >= off) ? sc[t - off] : 0;
        __syncthreads();
        sc[t] += u;
        __syncthreads();
    }
    if (t < nb) {
        int ex = sc[t] - v;
        bstart[t] = ex;
        bcursor[t] = ex;
    }
    if (t == 0) bstart[nb] = e_cnt;
}

// ---- pass 1: LDS-staged binning into coarse buckets (contiguous writes) ----
__global__ __launch_bounds__(512) void bin_kernel(const int* __restrict__ ei,
                                                  int* __restrict__ bcursor,
                                                  unsigned* __restrict__ ebuf,
                                                  int e_cnt, int nb) {
    __shared__ int cnt[NBMAX];
    __shared__ int ex[NBMAX];
    __shared__ int gbase[NBMAX];
    __shared__ unsigned stage[CH1];
    int t = threadIdx.x;
    cnt[t] = 0;
    __syncthreads();
    int base = blockIdx.x * CH1;
    int m = min(CH1, e_cnt - base);

    unsigned pack[4];
    int rank[4], bkt[4];
    int nk = 0;
#pragma unroll
    for (int k = 0; k < 4; ++k) {
        int idx = t + k * 512;
        if (idx < m) {
            int e = base + idx;
            int r = ei[e];
            int c = ei[e_cnt + e];
            unsigned p = ((unsigned)r << 16) | (unsigned)c;
            int b = r >> 7;
            pack[nk] = p;
            bkt[nk] = b;
            rank[nk] = atomicAdd(&cnt[b], 1);
            ++nk;
        }
    }
    __syncthreads();
    int v = cnt[t];
    ex[t] = v;
    __syncthreads();
    for (int off = 1; off < 512; off <<= 1) {
        int u = (t >= off) ? ex[t - off] : 0;
        __syncthreads();
        ex[t] += u;
        __syncthreads();
    }
    int excl = ex[t] - v;
    if (t < nb && v > 0) gbase[t] = atomicAdd(&bcursor[t], v);
    __syncthreads();
    ex[t] = excl;
    __syncthreads();
    for (int k = 0; k < nk; ++k) stage[ex[bkt[k]] + rank[k]] = pack[k];
    __syncthreads();
    for (int s = t; s < m; s += 512) {
        unsigned p = stage[s];
        int b = p >> 23;
        ebuf[gbase[b] + (s - ex[b])] = p;
    }
}

// ---- merged sort+softmax+aggregate: block = one full bucket (128 rows, 1024 thr) ----
__global__ __launch_bounds__(1024) void agg_kernel(const unsigned* __restrict__ ebuf,
                                                   const int* __restrict__ bstart,
                                                   const float* __restrict__ s1,
                                                   const float* __restrict__ s2,
                                                   const unsigned* __restrict__ Whb,
                                                   const unsigned* __restrict__ maxslot,
                                                   float* __restrict__ out, int n) {
    __shared__ unsigned stage[CAPB];   // 12 KB: row-sorted packed (row|col)
    __shared__ float evs[CAPB];        // 12 KB: exp -> normalized alpha
    __shared__ int cnt[128];
    __shared__ int exs[128];
    __shared__ float invs[128];
    __shared__ float s1l[128];
    int b = blockIdx.x;
    int t = threadIdx.x;
    int row0 = b << 7;
    int start = bstart[b];
    int m = min(bstart[b + 1] - start, CAPB);

    if (t < 128) {
        cnt[t] = 0;
        int gr = row0 + t;
        s1l[t] = (gr < n) ? s1[gr] : 0.f;
    }
    __syncthreads();
    for (int i = t; i < m; i += 1024)
        atomicAdd(&cnt[(ebuf[start + i] >> 16) & 127], 1);
    __syncthreads();
    int v = (t < 128) ? cnt[t] : 0;
    if (t < 128) exs[t] = v;
    __syncthreads();
    for (int off = 1; off < 128; off <<= 1) {
        int u = (t < 128 && t >= off) ? exs[t - off] : 0;
        __syncthreads();
        if (t < 128) exs[t] += u;
        __syncthreads();
    }
    if (t < 128) { exs[t] -= v; cnt[t] = 0; }
    __syncthreads();
    for (int i = t; i < m; i += 1024) {
        unsigned p = ebuf[start + i];
        int lr = (p >> 16) & 127;
        int rk = atomicAdd(&cnt[lr], 1);
        stage[exs[lr] + rk] = p;
    }
    __syncthreads();

    float M = fdec(maxslot[0]) + fdec(maxslot[1]);
    M = (M >= 0.f) ? M : 0.2f * M;   // leaky(upper bound) >= true max score

    for (int i = t; i < m; i += 1024) {
        unsigned p = stage[i];
        float sv = s1l[(p >> 16) & 127] + s2[p & 0xFFFFu];
        float le = (sv >= 0.f) ? sv : 0.2f * sv;
        evs[i] = expf(le - M);
    }
    __syncthreads();
    if (t < 128) {
        int s0 = exs[t], d = cnt[t];
        float s = 0.f;
        for (int k = 0; k < d; ++k) s += evs[s0 + k];
        invs[t] = 1.0f / (s + 1e-10f);
    }
    __syncthreads();
    for (int i = t; i < m; i += 1024)
        evs[i] *= invs[(stage[i] >> 16) & 127];
    __syncthreads();

    int w = t >> 6, l = t & 63, half = l >> 5, fl = l & 31;
    for (int ni = (w << 3); ni < (w << 3) + 8; ++ni) {
        int node = row0 + ni;
        if (node >= n) break;
        int s0 = exs[ni], deg = cnt[ni];
        float4 acc = make_float4(0.f, 0.f, 0.f, 0.f);
        int j = half;
        for (; j + 2 < deg; j += 4) {
            unsigned c0 = stage[s0 + j] & 0xFFFFu;
            unsigned c1 = stage[s0 + j + 2] & 0xFFFFu;
            float a0 = evs[s0 + j], a1 = evs[s0 + j + 2];
            uint2 b0 = *(const uint2*)(Whb + (size_t)c0 * 64 + 2 * fl);
            uint2 b1 = *(const uint2*)(Whb + (size_t)c1 * 64 + 2 * fl);
            acc.x = fmaf(a0, __uint_as_float(b0.x << 16), acc.x);
            acc.y = fmaf(a0, __uint_as_float(b0.x & 0xFFFF0000u), acc.y);
            acc.z = fmaf(a0, __uint_as_float(b0.y << 16), acc.z);
            acc.w = fmaf(a0, __uint_as_float(b0.y & 0xFFFF0000u), acc.w);
            acc.x = fmaf(a1, __uint_as_float(b1.x << 16), acc.x);
            acc.y = fmaf(a1, __uint_as_float(b1.x & 0xFFFF0000u), acc.y);
            acc.z = fmaf(a1, __uint_as_float(b1.y << 16), acc.z);
            acc.w = fmaf(a1, __uint_as_float(b1.y & 0xFFFF0000u), acc.w);
        }
        if (j < deg) {
            unsigned c0 = stage[s0 + j] & 0xFFFFu;
            float a0 = evs[s0 + j];
            uint2 b0 = *(const uint2*)(Whb + (size_t)c0 * 64 + 2 * fl);
            acc.x = fmaf(a0, __uint_as_float(b0.x << 16), acc.x);
            acc.y = fmaf(a0, __uint_as_float(b0.x & 0xFFFF0000u), acc.y);
            acc.z = fmaf(a0, __uint_as_float(b0.y << 16), acc.z);
            acc.w = fmaf(a0, __uint_as_float(b0.y & 0xFFFF0000u), acc.w);
        }
        acc.x += __shfl_xor(acc.x, 32, 64);
        acc.y += __shfl_xor(acc.y, 32, 64);
        acc.z += __shfl_xor(acc.z, 32, 64);
        acc.w += __shfl_xor(acc.w, 32, 64);
        if (half == 0) {
            float4 r;
            r.x = (acc.x > 0.f) ? acc.x : expm1f(acc.x);
            r.y = (acc.y > 0.f) ? acc.y : expm1f(acc.y);
            r.z = (acc.z > 0.f) ? acc.z : expm1f(acc.z);
            r.w = (acc.w > 0.f) ? acc.w : expm1f(acc.w);
            ((float4*)(out + (size_t)node * FD))[fl] = r;
        }
    }
}

extern "C" void kernel_launch(void* const* d_in, const int* in_sizes, int n_in,
                              void* d_out, int out_size, void* d_ws, size_t ws_size,
                              hipStream_t stream) {
    const float* h = (const float*)d_in[0];
    const int* ei  = (const int*)d_in[1];
    const float* W = (const float*)d_in[2];
    const float* a = (const float*)d_in[3];
    float* out = (float*)d_out;
    int n = in_sizes[0] / FD;   // 50000
    int e = in_sizes[1] / 2;    // 800000
    int nb = (n + 127) >> 7;    // coarse buckets (requires n <= 65536)

    char* ws = (char*)d_ws;
    size_t off = 0;
    auto alloc = [&](size_t bytes) -> void* {
        void* p = ws + off;
        off += bytes;
        off = (off + 255) & ~(size_t)255;
        return p;
    };
    unsigned* Whb     = (unsigned*)alloc((size_t)n * 64 * sizeof(unsigned));  // bf16 Wh
    unsigned* Wb      = (unsigned*)alloc((size_t)FD * 64 * sizeof(unsigned)); // bf16 W
    float*    s1      = (float*)alloc((size_t)n * sizeof(float));
    float*    s2      = (float*)alloc((size_t)n * sizeof(float));
    int*      bhist   = (int*)alloc((size_t)NBMAX * sizeof(int));
    int*      bstart  = (int*)alloc((size_t)(NBMAX + 1) * sizeof(int));
    int*      bcursor = (int*)alloc((size_t)NBMAX * sizeof(int));
    unsigned* ebuf    = (unsigned*)alloc((size_t)e * sizeof(unsigned));
    unsigned* maxslot = (unsigned*)alloc(2 * sizeof(unsigned));

    int eblocks = (e + CH1 - 1) / CH1;

    initwt_kernel<<<FD, FD, 0, stream>>>(W, Wb, bhist, maxslot);
    bhist_kernel<<<eblocks, 256, 0, stream>>>(ei, bhist, e, nb);
    gemm_kernel<<<(n + 63) / 64, 256, 0, stream>>>(h, Wb, Whb, n);
    s12_kernel<<<128, 256, 0, stream>>>(Whb, a, s1, s2, maxslot, n);
    bscan_kernel<<<1, 512, 0, stream>>>(bhist, bstart, bcursor, nb, e);
    bin_kernel<<<eblocks, 512, 0, stream>>>(ei, bcursor, ebuf, e, nb);
    agg_kernel<<<nb, 1024, 0, stream>>>(ebuf, bstart, s1, s2, Whb, maxslot, out, n);
}

// Round 9
// 170.595 us; speedup vs baseline: 1.2790x; 1.2790x over previous
//
#include <hip/hip_runtime.h>

constexpr int FD = 128;
constexpr int NBMAX = 512;   // max coarse buckets (rows/128); n<=65536
constexpr int CH1 = 2048;    // edges per binning block
constexpr int CAPB = 3072;   // per-bucket edge capacity (mean 2048, +22 sigma)

typedef __attribute__((ext_vector_type(8))) short short8;   // 8 bf16 (4 VGPRs)
typedef __attribute__((ext_vector_type(4))) float floatx4;  // MFMA acc

// ---- monotone float<->uint encoding for atomic max over floats ----
__device__ __forceinline__ unsigned fenc(float f) {
    unsigned u = __float_as_uint(f);
    return (u & 0x80000000u) ? ~u : (u | 0x80000000u);
}
__device__ __forceinline__ float fdec(unsigned e) {
    return (e & 0x80000000u) ? __uint_as_float(e & 0x7fffffffu)
                             : __uint_as_float(~e);
}

// RNE pack of two fp32 -> bf16 pair (x in low 16, y in high 16)
__device__ __forceinline__ unsigned bpack(float x, float y) {
    unsigned ux = __float_as_uint(x); ux += 0x7FFFu + ((ux >> 16) & 1u);
    unsigned uy = __float_as_uint(y); uy += 0x7FFFu + ((uy >> 16) & 1u);
    return (ux >> 16) | (uy & 0xFFFF0000u);
}

// ---- W -> bf16 rows (Wb) + zero bucket histogram + init max slots ----
__global__ __launch_bounds__(128) void initwt_kernel(const float* __restrict__ W,
                                                     unsigned* __restrict__ Wb,
                                                     int* __restrict__ bhist,
                                                     unsigned* __restrict__ maxslot) {
    int j = blockIdx.x, k = threadIdx.x;
    float w = W[(size_t)j * FD + k];
    float pw = __shfl_xor(w, 1, 64);             // partner k^1 (same wave)
    if ((k & 1) == 0) Wb[(size_t)j * 64 + (k >> 1)] = bpack(w, pw);
    if (j == 0) {
        for (int i = k; i < NBMAX; i += 128) bhist[i] = 0;
        if (k < 2) maxslot[k] = 0x007FFFFFu;     // fenc(-inf)
    }
}

// ---- MFMA GEMM: Whb(bf16) = h @ W^T ; fused s1/s2 epilogue from fp32 accs ----
// block = 256 thr = 4 waves; wave = 16 rows x 128 cols (8 col-tiles x 4 K-steps)
__global__ __launch_bounds__(256) void gemm_kernel(const float* __restrict__ h,
                                                   const unsigned* __restrict__ Wb,
                                                   const float* __restrict__ a,
                                                   unsigned* __restrict__ Whb,
                                                   float* __restrict__ s1,
                                                   float* __restrict__ s2, int n) {
    int w = threadIdx.x >> 6, lane = threadIdx.x & 63;
    int quad = lane >> 4, c = lane & 15;
    int rbase = blockIdx.x * 64 + w * 16;

    // A frags: lane holds h[rbase + c][k], k = kk*32 + quad*8 + (0..7), bf16-cast
    int arow = min(rbase + c, n - 1);
    const float4* hrow = (const float4*)(h + (size_t)arow * FD);
    union { uint4 u; short8 s; } af[4];
#pragma unroll
    for (int kk = 0; kk < 4; ++kk) {
        int k0 = kk * 32 + quad * 8;
        float4 f0 = hrow[k0 >> 2];
        float4 f1 = hrow[(k0 >> 2) + 1];
        af[kk].u.x = bpack(f0.x, f0.y);
        af[kk].u.y = bpack(f0.z, f0.w);
        af[kk].u.z = bpack(f1.x, f1.y);
        af[kk].u.w = bpack(f1.z, f1.w);
    }

    float p1a[4] = {0.f, 0.f, 0.f, 0.f};
    float p2a[4] = {0.f, 0.f, 0.f, 0.f};

#pragma unroll
    for (int t = 0; t < 8; ++t) {
        // B frag: lane holds W[t*16 + c][k], k = kk*32 + quad*8 + (0..7)  (L1-resident)
        const uint4* brow = (const uint4*)(Wb + (size_t)(t * 16 + c) * 64 + quad * 4);
        floatx4 acc = {0.f, 0.f, 0.f, 0.f};
#pragma unroll
        for (int kk = 0; kk < 4; ++kk) {
            union { uint4 u; short8 s; } bf;
            bf.u = brow[kk * 4];   // +kk*32 bf16 = +kk*16 uint = +kk*4 uint4
            acc = __builtin_amdgcn_mfma_f32_16x16x32_bf16(af[kk].s, bf.s, acc, 0, 0, 0);
        }
        // D layout: col j = t*16 + (lane&15), row = quad*4 + i
        float a1v = a[t * 16 + c];
        float a2v = a[FD + t * 16 + c];
#pragma unroll
        for (int i = 0; i < 4; ++i) {
            float v = acc[i];
            p1a[i] = fmaf(v, a1v, p1a[i]);
            p2a[i] = fmaf(v, a2v, p2a[i]);
            float pv = __shfl_xor(v, 1, 64);     // partner col j^1
            int r = rbase + quad * 4 + i;
            if ((c & 1) == 0 && r < n)
                Whb[(size_t)r * 64 + t * 8 + (c >> 1)] = bpack(v, pv);
        }
    }

    // reduce p1/p2 over the 16 col-lanes of each quad; lane c=0 writes 4 rows
#pragma unroll
    for (int d = 1; d < 16; d <<= 1) {
#pragma unroll
        for (int i = 0; i < 4; ++i) {
            p1a[i] += __shfl_xor(p1a[i], d, 64);
            p2a[i] += __shfl_xor(p2a[i], d, 64);
        }
    }
    if (c == 0) {
#pragma unroll
        for (int i = 0; i < 4; ++i) {
            int r = rbase + quad * 4 + i;
            if (r < n) { s1[r] = p1a[i]; s2[r] = p2a[i]; }
        }
    }
}

// ---- grid-stride max-reduce of s1/s2 -> maxslot (2 atomics per block) ----
__global__ __launch_bounds__(256) void smax_kernel(const float* __restrict__ s1,
                                                   const float* __restrict__ s2,
                                                   unsigned* __restrict__ maxslot, int n) {
    __shared__ float m1s[4], m2s[4];
    int t = threadIdx.x, lane = t & 63, wid = t >> 6;
    float m1 = -3.0e38f, m2 = -3.0e38f;
    for (int i = blockIdx.x * 256 + t; i < n; i += gridDim.x * 256) {
        m1 = fmaxf(m1, s1[i]);
        m2 = fmaxf(m2, s2[i]);
    }
#pragma unroll
    for (int d = 1; d < 64; d <<= 1) {
        m1 = fmaxf(m1, __shfl_xor(m1, d, 64));
        m2 = fmaxf(m2, __shfl_xor(m2, d, 64));
    }
    if (lane == 0) { m1s[wid] = m1; m2s[wid] = m2; }
    __syncthreads();
    if (t == 0) {
        m1 = fmaxf(fmaxf(m1s[0], m1s[1]), fmaxf(m1s[2], m1s[3]));
        m2 = fmaxf(fmaxf(m2s[0], m2s[1]), fmaxf(m2s[2], m2s[3]));
        atomicMax(&maxslot[0], fenc(m1));
        atomicMax(&maxslot[1], fenc(m2));
    }
}

// ---- pass A: coarse bucket histogram (bucket = row >> 7), LDS-staged ----
__global__ __launch_bounds__(256) void bhist_kernel(const int* __restrict__ ei,
                                                    int* __restrict__ bhist,
                                                    int e_cnt, int nb) {
    __shared__ int h[NBMAX];
    int t = threadIdx.x;
    for (int i = t; i < NBMAX; i += 256) h[i] = 0;
    __syncthreads();
    int base = blockIdx.x * CH1;
    int m = min(CH1, e_cnt - base);
    for (int idx = t; idx < m; idx += 256) {
        int r = ei[base + idx];
        atomicAdd(&h[r >> 7], 1);
    }
    __syncthreads();
    for (int i = t; i < nb; i += 256)
        if (h[i]) atomicAdd(&bhist[i], h[i]);
}

// ---- scan bucket counts -> bstart / bcursor ----
__global__ __launch_bounds__(512) void bscan_kernel(const int* __restrict__ bhist,
                                                    int* __restrict__ bstart,
                                                    int* __restrict__ bcursor,
                                                    int nb, int e_cnt) {
    __shared__ int sc[512];
    int t = threadIdx.x;
    int v = (t < nb) ? bhist[t] : 0;
    sc[t] = v;
    __syncthreads();
    for (int off = 1; off < 512; off <<= 1) {
        int u = (t >= off) ? sc[t - off] : 0;
        __syncthreads();
        sc[t] += u;
        __syncthreads();
    }
    if (t < nb) {
        int ex = sc[t] - v;
        bstart[t] = ex;
        bcursor[t] = ex;
    }
    if (t == 0) bstart[nb] = e_cnt;
}

// ---- pass 1: LDS-staged binning into coarse buckets (contiguous writes) ----
__global__ __launch_bounds__(512) void bin_kernel(const int* __restrict__ ei,
                                                  int* __restrict__ bcursor,
                                                  unsigned* __restrict__ ebuf,
                                                  int e_cnt, int nb) {
    __shared__ int cnt[NBMAX];
    __shared__ int ex[NBMAX];
    __shared__ int gbase[NBMAX];
    __shared__ unsigned stage[CH1];
    int t = threadIdx.x;
    cnt[t] = 0;
    __syncthreads();
    int base = blockIdx.x * CH1;
    int m = min(CH1, e_cnt - base);

    unsigned pack[4];
    int rank[4], bkt[4];
    int nk = 0;
#pragma unroll
    for (int k = 0; k < 4; ++k) {
        int idx = t + k * 512;
        if (idx < m) {
            int e = base + idx;
            int r = ei[e];
            int c = ei[e_cnt + e];
            unsigned p = ((unsigned)r << 16) | (unsigned)c;
            int b = r >> 7;
            pack[nk] = p;
            bkt[nk] = b;
            rank[nk] = atomicAdd(&cnt[b], 1);
            ++nk;
        }
    }
    __syncthreads();
    int v = cnt[t];
    ex[t] = v;
    __syncthreads();
    for (int off = 1; off < 512; off <<= 1) {
        int u = (t >= off) ? ex[t - off] : 0;
        __syncthreads();
        ex[t] += u;
        __syncthreads();
    }
    int excl = ex[t] - v;
    if (t < nb && v > 0) gbase[t] = atomicAdd(&bcursor[t], v);
    __syncthreads();
    ex[t] = excl;
    __syncthreads();
    for (int k = 0; k < nk; ++k) stage[ex[bkt[k]] + rank[k]] = pack[k];
    __syncthreads();
    for (int s = t; s < m; s += 512) {
        unsigned p = stage[s];
        int b = p >> 23;
        ebuf[gbase[b] + (s - ex[b])] = p;
    }
}

// ---- merged sort+softmax+aggregate: block = one full bucket (128 rows, 1024 thr) ----
__global__ __launch_bounds__(1024) void agg_kernel(const unsigned* __restrict__ ebuf,
                                                   const int* __restrict__ bstart,
                                                   const float* __restrict__ s1,
                                                   const float* __restrict__ s2,
                                                   const unsigned* __restrict__ Whb,
                                                   const unsigned* __restrict__ maxslot,
                                                   float* __restrict__ out, int n) {
    __shared__ unsigned stage[CAPB];   // 12 KB: row-sorted packed (row|col)
    __shared__ float evs[CAPB];        // 12 KB: exp -> normalized alpha
    __shared__ int cnt[128];
    __shared__ int exs[128];
    __shared__ float invs[128];
    __shared__ float s1l[128];
    int b = blockIdx.x;
    int t = threadIdx.x;
    int row0 = b << 7;
    int start = bstart[b];
    int m = min(bstart[b + 1] - start, CAPB);

    if (t < 128) {
        cnt[t] = 0;
        int gr = row0 + t;
        s1l[t] = (gr < n) ? s1[gr] : 0.f;
    }
    __syncthreads();
    for (int i = t; i < m; i += 1024)
        atomicAdd(&cnt[(ebuf[start + i] >> 16) & 127], 1);
    __syncthreads();
    int v = (t < 128) ? cnt[t] : 0;
    if (t < 128) exs[t] = v;
    __syncthreads();
    for (int off = 1; off < 128; off <<= 1) {
        int u = (t < 128 && t >= off) ? exs[t - off] : 0;
        __syncthreads();
        if (t < 128) exs[t] += u;
        __syncthreads();
    }
    if (t < 128) { exs[t] -= v; cnt[t] = 0; }
    __syncthreads();
    for (int i = t; i < m; i += 1024) {
        unsigned p = ebuf[start + i];
        int lr = (p >> 16) & 127;
        int rk = atomicAdd(&cnt[lr], 1);
        stage[exs[lr] + rk] = p;
    }
    __syncthreads();

    float M = fdec(maxslot[0]) + fdec(maxslot[1]);
    M = (M >= 0.f) ? M : 0.2f * M;   // leaky(upper bound) >= true max score

    for (int i = t; i < m; i += 1024) {
        unsigned p = stage[i];
        float sv = s1l[(p >> 16) & 127] + s2[p & 0xFFFFu];
        float le = (sv >= 0.f) ? sv : 0.2f * sv;
        evs[i] = expf(le - M);
    }
    __syncthreads();
    if (t < 128) {
        int s0 = exs[t], d = cnt[t];
        float s = 0.f;
        for (int k = 0; k < d; ++k) s += evs[s0 + k];
        invs[t] = 1.0f / (s + 1e-10f);
    }
    __syncthreads();
    for (int i = t; i < m; i += 1024)
        evs[i] *= invs[(stage[i] >> 16) & 127];
    __syncthreads();

    int w = t >> 6, l = t & 63, half = l >> 5, fl = l & 31;
    for (int ni = (w << 3); ni < (w << 3) + 8; ++ni) {
        int node = row0 + ni;
        if (node >= n) break;
        int s0 = exs[ni], deg = cnt[ni];
        float4 acc = make_float4(0.f, 0.f, 0.f, 0.f);
        int j = half;
        for (; j + 2 < deg; j += 4) {
            unsigned c0 = stage[s0 + j] & 0xFFFFu;
            unsigned c1 = stage[s0 + j + 2] & 0xFFFFu;
            float a0 = evs[s0 + j], a1 = evs[s0 + j + 2];
            uint2 b0 = *(const uint2*)(Whb + (size_t)c0 * 64 + 2 * fl);
            uint2 b1 = *(const uint2*)(Whb + (size_t)c1 * 64 + 2 * fl);
            acc.x = fmaf(a0, __uint_as_float(b0.x << 16), acc.x);
            acc.y = fmaf(a0, __uint_as_float(b0.x & 0xFFFF0000u), acc.y);
            acc.z = fmaf(a0, __uint_as_float(b0.y << 16), acc.z);
            acc.w = fmaf(a0, __uint_as_float(b0.y & 0xFFFF0000u), acc.w);
            acc.x = fmaf(a1, __uint_as_float(b1.x << 16), acc.x);
            acc.y = fmaf(a1, __uint_as_float(b1.x & 0xFFFF0000u), acc.y);
            acc.z = fmaf(a1, __uint_as_float(b1.y << 16), acc.z);
            acc.w = fmaf(a1, __uint_as_float(b1.y & 0xFFFF0000u), acc.w);
        }
        if (j < deg) {
            unsigned c0 = stage[s0 + j] & 0xFFFFu;
            float a0 = evs[s0 + j];
            uint2 b0 = *(const uint2*)(Whb + (size_t)c0 * 64 + 2 * fl);
            acc.x = fmaf(a0, __uint_as_float(b0.x << 16), acc.x);
            acc.y = fmaf(a0, __uint_as_float(b0.x & 0xFFFF0000u), acc.y);
            acc.z = fmaf(a0, __uint_as_float(b0.y << 16), acc.z);
            acc.w = fmaf(a0, __uint_as_float(b0.y & 0xFFFF0000u), acc.w);
        }
        acc.x += __shfl_xor(acc.x, 32, 64);
        acc.y += __shfl_xor(acc.y, 32, 64);
        acc.z += __shfl_xor(acc.z, 32, 64);
        acc.w += __shfl_xor(acc.w, 32, 64);
        if (half == 0) {
            float4 r;
            r.x = (acc.x > 0.f) ? acc.x : expm1f(acc.x);
            r.y = (acc.y > 0.f) ? acc.y : expm1f(acc.y);
            r.z = (acc.z > 0.f) ? acc.z : expm1f(acc.z);
            r.w = (acc.w > 0.f) ? acc.w : expm1f(acc.w);
            ((float4*)(out + (size_t)node * FD))[fl] = r;
        }
    }
}

extern "C" void kernel_launch(void* const* d_in, const int* in_sizes, int n_in,
                              void* d_out, int out_size, void* d_ws, size_t ws_size,
                              hipStream_t stream) {
    const float* h = (const float*)d_in[0];
    const int* ei  = (const int*)d_in[1];
    const float* W = (const float*)d_in[2];
    const float* a = (const float*)d_in[3];
    float* out = (float*)d_out;
    int n = in_sizes[0] / FD;   // 50000
    int e = in_sizes[1] / 2;    // 800000
    int nb = (n + 127) >> 7;    // coarse buckets (requires n <= 65536)

    char* ws = (char*)d_ws;
    size_t off = 0;
    auto alloc = [&](size_t bytes) -> void* {
        void* p = ws + off;
        off += bytes;
        off = (off + 255) & ~(size_t)255;
        return p;
    };
    unsigned* Whb     = (unsigned*)alloc((size_t)n * 64 * sizeof(unsigned));  // bf16 Wh
    unsigned* Wb      = (unsigned*)alloc((size_t)FD * 64 * sizeof(unsigned)); // bf16 W
    float*    s1      = (float*)alloc((size_t)n * sizeof(float));
    float*    s2      = (float*)alloc((size_t)n * sizeof(float));
    int*      bhist   = (int*)alloc((size_t)NBMAX * sizeof(int));
    int*      bstart  = (int*)alloc((size_t)(NBMAX + 1) * sizeof(int));
    int*      bcursor = (int*)alloc((size_t)NBMAX * sizeof(int));
    unsigned* ebuf    = (unsigned*)alloc((size_t)e * sizeof(unsigned));
    unsigned* maxslot = (unsigned*)alloc(2 * sizeof(unsigned));

    int eblocks = (e + CH1 - 1) / CH1;

    initwt_kernel<<<FD, FD, 0, stream>>>(W, Wb, bhist, maxslot);
    bhist_kernel<<<eblocks, 256, 0, stream>>>(ei, bhist, e, nb);
    gemm_kernel<<<(n + 63) / 64, 256, 0, stream>>>(h, Wb, a, Whb, s1, s2, n);
    smax_kernel<<<104, 256, 0, stream>>>(s1, s2, maxslot, n);
    bscan_kernel<<<1, 512, 0, stream>>>(bhist, bstart, bcursor, nb, e);
    bin_kernel<<<eblocks, 512, 0, stream>>>(ei, bcursor, ebuf, e, nb);
    agg_kernel<<<nb, 1024, 0, stream>>>(ebuf, bstart, s1, s2, Whb, maxslot, out, n);
}